// Round 1
// baseline (1057.917 us; speedup 1.0000x reference)
//
#include <hip/hip_runtime.h>
#include <stdint.h>

#define NHEADS 16
#define LKK 8192
#define SPLIT 8
#define PSTR 72  // padded LDS row stride (shorts) for P tiles: conflict-free b128 reads

typedef __attribute__((ext_vector_type(8))) short short8;
typedef __attribute__((ext_vector_type(4))) float f32x4;
typedef __attribute__((ext_vector_type(4))) unsigned short ushort4v;

__device__ __forceinline__ unsigned short f2bf(float f) {
  union { float f; unsigned u; } v; v.f = f;
  unsigned u = v.u;
  return (unsigned short)((u + 0x7fffu + ((u >> 16) & 1u)) >> 16);
}

__device__ __forceinline__ void async_ld16(const void* g, void* l) {
  __builtin_amdgcn_global_load_lds(
      (const __attribute__((address_space(1))) unsigned int*)g,
      (__attribute__((address_space(3))) unsigned int*)l, 16, 0, 0);
}

// Convert up to two fp32 tensors to bf16. gridDim.y selects tensor; each
// block handles 1024 elements (256 threads x float4).
__global__ __launch_bounds__(256) void cvt2(const float* __restrict__ a,
                                            const float* __restrict__ b,
                                            unsigned short* __restrict__ oa,
                                            unsigned short* __restrict__ ob) {
  const float* s = blockIdx.y ? b : a;
  unsigned short* d = blockIdx.y ? ob : oa;
  const size_t i = ((size_t)blockIdx.x * 256 + threadIdx.x) * 4;
  float4 v = *(const float4*)(s + i);
  ushort4v o = {f2bf(v.x), f2bf(v.y), f2bf(v.z), f2bf(v.w)};
  *(ushort4v*)(d + i) = o;
}

// C = A(bf16,[M x 1024]) @ Bw(bf16,[1024 x 1024])^T + bias, NT GEMM.
// 128x128 tile, 4 waves, both operands staged via global_load_lds width-16.
// MODE 0: fp32 row-major out. MODE 1: bf16 out [b][h][x][d] (x = 1<<LOG2ROWS).
// MODE 2: bf16 out transposed [b][h][d][x].
// Block remap: linearize dispatch id, XCD-swizzle (id%8 -> contiguous chunk),
// then bn = fastest-varying -> 8 consecutive blocks on ONE XCD share one
// A row-tile (256KB, L2-resident) and that XCD sees the full weight matrix
// (2MB, L2-resident). Requires gridDim.y == 8 (true for all launches).
template <int MODE, int LOG2ROWS>
__global__ __launch_bounds__(256) void gemm_nt(
    const unsigned short* __restrict__ A, const unsigned short* __restrict__ Bw,
    const float* __restrict__ bias, float scale, void* __restrict__ outp) {
  __shared__ unsigned short As[128 * 32];
  __shared__ unsigned short Bs[128 * 32];

  const int tid = threadIdx.x;
  const int wave = tid >> 6, lane = tid & 63;
  const int quad = lane >> 4, l16 = lane & 15;
  const int wr = wave >> 1, wc = wave & 1;

  const int gx = gridDim.x;
  const int nwg = gx * 8;                 // gridDim.y == 8 always
  int id = blockIdx.y * gx + blockIdx.x;  // dispatch order (x fastest)
  const int cpx = nwg >> 3;               // nwg % 8 == 0 for all launches
  id = (id & 7) * cpx + (id >> 3);        // bijective XCD chunking
  const int bm = id >> 3, bn = id & 7;

  f32x4 acc[4][4] = {};

  // Staging: wave w covers tile rows [w*32, w*32+32). Lane i -> row (i>>2),
  // 8-elem segment (i&3). LDS side is wave-uniform base + lane*16B, which
  // lands lane i at shorts [i*8, i*8+8) of a row-major [32][32] wave chunk.
  const int srow = lane >> 2;
  const int sseg = lane & 3;
  const unsigned short* Ag =
      A + (size_t)(bm * 128 + wave * 32 + srow) * 1024 + sseg * 8;
  const unsigned short* Bg =
      Bw + (size_t)(bn * 128 + wave * 32 + srow) * 1024 + sseg * 8;
  unsigned short* AsW = As + wave * 32 * 32;
  unsigned short* BsW = Bs + wave * 32 * 32;

  for (int kk = 0; kk < 32; ++kk) {
    const int k0 = kk * 32;
    __syncthreads();  // protect LDS from previous iter's readers
    async_ld16(Ag + k0, AsW);
    async_ld16(Ag + 16 * 1024 + k0, AsW + 16 * 32);
    async_ld16(Bg + k0, BsW);
    async_ld16(Bg + 16 * 1024 + k0, BsW + 16 * 32);
    __syncthreads();  // drains vmcnt for the async staging

    short8 af[4], bf[4];
#pragma unroll
    for (int i = 0; i < 4; ++i)
      af[i] = *(const short8*)(As + (wr * 64 + i * 16 + l16) * 32 + quad * 8);
#pragma unroll
    for (int j = 0; j < 4; ++j)
      bf[j] = *(const short8*)(Bs + (wc * 64 + j * 16 + l16) * 32 + quad * 8);
#pragma unroll
    for (int i = 0; i < 4; ++i)
#pragma unroll
      for (int j = 0; j < 4; ++j)
        acc[i][j] =
            __builtin_amdgcn_mfma_f32_16x16x32_bf16(af[i], bf[j], acc[i][j], 0, 0, 0);
  }

  float bvals[4];
#pragma unroll
  for (int j = 0; j < 4; ++j) bvals[j] = bias[bn * 128 + wc * 64 + j * 16 + l16];

#pragma unroll
  for (int i = 0; i < 4; ++i) {
    const int gm0 = bm * 128 + wr * 64 + i * 16 + quad * 4;
#pragma unroll
    for (int j = 0; j < 4; ++j) {
      const int gn = bn * 128 + wc * 64 + j * 16 + l16;
      float vals[4];
#pragma unroll
      for (int r = 0; r < 4; ++r) vals[r] = (acc[i][j][r] + bvals[j]) * scale;
      if constexpr (MODE == 0) {
        float* O = (float*)outp;
#pragma unroll
        for (int r = 0; r < 4; ++r) O[(size_t)(gm0 + r) * 1024 + gn] = vals[r];
      } else if constexpr (MODE == 1) {
        unsigned short* O = (unsigned short*)outp;
        const int h = gn >> 6, d = gn & 63;
#pragma unroll
        for (int r = 0; r < 4; ++r) {
          const int m = gm0 + r;
          const int bb = m >> LOG2ROWS;
          const int x = m & ((1 << LOG2ROWS) - 1);
          O[((((size_t)(bb * 16 + h)) << LOG2ROWS) + x) * 64 + d] = f2bf(vals[r]);
        }
      } else {
        unsigned short* O = (unsigned short*)outp;
        const int h = gn >> 6, d = gn & 63;
        const int bb = gm0 >> LOG2ROWS;
        const int x = gm0 & ((1 << LOG2ROWS) - 1);
        ushort4v pk = {f2bf(vals[0]), f2bf(vals[1]), f2bf(vals[2]), f2bf(vals[3])};
        *(ushort4v*)(O + ((((size_t)(bb * 16 + h)) * 64 + d) << LOG2ROWS) + x) = pk;
      }
    }
  }
}

// Split-K flash attention: grid (h=16, b=8, s=SPLIT), 256 threads.
// Block (h,b,s) covers keys [s*1024, +1024); wave w owns 256 of them.
// KVBLK=64 per iteration; l-sum kept per-lane (alpha is row-uniform so the
// online-softmax recurrence distributes over lanes) and reduced once at end.
// Writes unnormalized partials (m, l, O) per split.
__global__ __launch_bounds__(256) void attn_split(
    const unsigned short* __restrict__ q_hd,  // [B][H][16][64] bf16 (scale folded)
    const unsigned short* __restrict__ k_hd,  // [B][H][8192][64] bf16
    const unsigned short* __restrict__ v_t,   // [B][H][64][8192] bf16
    float* __restrict__ part_O,               // [B*H][SPLIT][16][64]
    float* __restrict__ part_ml)              // [B*H][SPLIT][2][16]
{
  __shared__ unsigned short p_lds[4][16 * PSTR];
  __shared__ float o_lds[4][16][64];
  __shared__ float ml_lds[4][2][16];

  const int h = blockIdx.x, b = blockIdx.y, sp = blockIdx.z;
  const int tid = threadIdx.x, wave = tid >> 6, lane = tid & 63;
  const int quad = lane >> 4, l16 = lane & 15;
  const size_t bh = (size_t)(b * NHEADS + h);
  const float LOG2E = 1.44269504088896f;

  const unsigned short* qb = q_hd + bh * (16 * 64) + l16 * 64 + quad * 8;
  short8 aq0 = *(const short8*)(qb);
  short8 aq1 = *(const short8*)(qb + 32);

  const unsigned short* kb_base = k_hd + bh * ((size_t)LKK * 64);
  const unsigned short* vb_base = v_t + bh * ((size_t)64 * LKK);

  float ms[4], ls[4];
  f32x4 o[4] = {};
#pragma unroll
  for (int r = 0; r < 4; ++r) { ms[r] = -3.0e38f; ls[r] = 0.f; }

  unsigned short* pw = &p_lds[wave][0];
  const int jbase = sp * (LKK / SPLIT) + wave * (LKK / SPLIT / 4);

  for (int c = 0; c < (LKK / SPLIT / 4) / 64; ++c) {
    const int j0 = jbase + c * 64;
    short8 kf[4][2];
#pragma unroll
    for (int jt = 0; jt < 4; ++jt)
#pragma unroll
      for (int dh = 0; dh < 2; ++dh)
        kf[jt][dh] = *(const short8*)(kb_base + (size_t)(j0 + jt * 16 + l16) * 64 +
                                      dh * 32 + quad * 8);
    f32x4 s[4];
#pragma unroll
    for (int jt = 0; jt < 4; ++jt) {
      f32x4 z = {};
      z = __builtin_amdgcn_mfma_f32_16x16x32_bf16(aq0, kf[jt][0], z, 0, 0, 0);
      z = __builtin_amdgcn_mfma_f32_16x16x32_bf16(aq1, kf[jt][1], z, 0, 0, 0);
      s[jt] = z;
    }
    float p[4][4], alpha[4];
#pragma unroll
    for (int r = 0; r < 4; ++r) {
      float v = fmaxf(fmaxf(s[0][r], s[1][r]), fmaxf(s[2][r], s[3][r]));
      v = fmaxf(v, __shfl_xor(v, 1));
      v = fmaxf(v, __shfl_xor(v, 2));
      v = fmaxf(v, __shfl_xor(v, 4));
      v = fmaxf(v, __shfl_xor(v, 8));
      const float mn = fmaxf(ms[r], v);
      alpha[r] = __builtin_amdgcn_exp2f((ms[r] - mn) * LOG2E);
      float rs = 0.f;
#pragma unroll
      for (int jt = 0; jt < 4; ++jt) {
        p[jt][r] = __builtin_amdgcn_exp2f((s[jt][r] - mn) * LOG2E);
        rs += p[jt][r];
      }
      ls[r] = ls[r] * alpha[r] + rs;  // per-lane partial; reduced at epilogue
      ms[r] = mn;
    }
#pragma unroll
    for (int dt = 0; dt < 4; ++dt) {
      f32x4 t = o[dt];
      t[0] *= alpha[0]; t[1] *= alpha[1]; t[2] *= alpha[2]; t[3] *= alpha[3];
      o[dt] = t;
    }
    // P: C-layout -> LDS (bf16, padded stride) -> A-layout
#pragma unroll
    for (int r = 0; r < 4; ++r)
#pragma unroll
      for (int jt = 0; jt < 4; ++jt)
        pw[(quad * 4 + r) * PSTR + jt * 16 + l16] = f2bf(p[jt][r]);
    short8 pa[2];
#pragma unroll
    for (int kt = 0; kt < 2; ++kt)
      pa[kt] = *(const short8*)(pw + l16 * PSTR + kt * 32 + quad * 8);
#pragma unroll
    for (int dt = 0; dt < 4; ++dt)
#pragma unroll
      for (int kt = 0; kt < 2; ++kt) {
        short8 vb = *(const short8*)(vb_base + (size_t)(dt * 16 + l16) * LKK + j0 +
                                     kt * 32 + quad * 8);
        o[dt] = __builtin_amdgcn_mfma_f32_16x16x32_bf16(pa[kt], vb, o[dt], 0, 0, 0);
      }
  }

  // deferred cross-lane l reduction (once, not per tile)
#pragma unroll
  for (int r = 0; r < 4; ++r) {
    ls[r] += __shfl_xor(ls[r], 1);
    ls[r] += __shfl_xor(ls[r], 2);
    ls[r] += __shfl_xor(ls[r], 4);
    ls[r] += __shfl_xor(ls[r], 8);
  }

#pragma unroll
  for (int dt = 0; dt < 4; ++dt)
#pragma unroll
    for (int r = 0; r < 4; ++r) o_lds[wave][quad * 4 + r][dt * 16 + l16] = o[dt][r];
  if (l16 == 0) {
#pragma unroll
    for (int r = 0; r < 4; ++r) {
      ml_lds[wave][0][quad * 4 + r] = ms[r];
      ml_lds[wave][1][quad * 4 + r] = ls[r];
    }
  }
  __syncthreads();

  const int q = tid >> 4;
  const int d0 = (tid & 15) * 4;
  float mstar = ml_lds[0][0][q];
#pragma unroll
  for (int w = 1; w < 4; ++w) mstar = fmaxf(mstar, ml_lds[w][0][q]);
  float lstar = 0.f, ov[4] = {0.f, 0.f, 0.f, 0.f};
#pragma unroll
  for (int w = 0; w < 4; ++w) {
    const float sc = __builtin_amdgcn_exp2f((ml_lds[w][0][q] - mstar) * LOG2E);
    lstar += ml_lds[w][1][q] * sc;
#pragma unroll
    for (int e = 0; e < 4; ++e) ov[e] += o_lds[w][q][d0 + e] * sc;
  }
  const size_t base = (bh * SPLIT + sp);
#pragma unroll
  for (int e = 0; e < 4; ++e) part_O[base * 1024 + q * 64 + d0 + e] = ov[e];
  if (d0 == 0) {
    part_ml[base * 32 + q] = mstar;
    part_ml[base * 32 + 16 + q] = lstar;
  }
}

// Merge SPLIT partials -> bf16 attn activations [B*16][1024] (row b*16+q, col h*64+d).
__global__ __launch_bounds__(256) void attn_merge(const float* __restrict__ part_O,
                                                  const float* __restrict__ part_ml,
                                                  unsigned short* __restrict__ attn_b) {
  const int bh = blockIdx.x;
  const int b = bh >> 4, h = bh & 15;
  const int q = threadIdx.x >> 4;
  const int d0 = (threadIdx.x & 15) * 4;
  const float LOG2E = 1.44269504088896f;

  float mstar = -3.0e38f;
#pragma unroll
  for (int s = 0; s < SPLIT; ++s)
    mstar = fmaxf(mstar, part_ml[((size_t)bh * SPLIT + s) * 32 + q]);
  float lsum = 0.f, ov[4] = {0.f, 0.f, 0.f, 0.f};
#pragma unroll
  for (int s = 0; s < SPLIT; ++s) {
    const size_t base = (size_t)bh * SPLIT + s;
    const float sc = __builtin_amdgcn_exp2f((part_ml[base * 32 + q] - mstar) * LOG2E);
    lsum += part_ml[base * 32 + 16 + q] * sc;
#pragma unroll
    for (int e = 0; e < 4; ++e) ov[e] += part_O[base * 1024 + q * 64 + d0 + e] * sc;
  }
  const float inv = 1.0f / lsum;
  ushort4v pk = {f2bf(ov[0] * inv), f2bf(ov[1] * inv), f2bf(ov[2] * inv),
                 f2bf(ov[3] * inv)};
  *(ushort4v*)(attn_b + (size_t)(b * 16 + q) * 1024 + h * 64 + d0) = pk;
}

extern "C" void kernel_launch(void* const* d_in, const int* in_sizes, int n_in,
                              void* d_out, int out_size, void* d_ws, size_t ws_size,
                              hipStream_t stream) {
  const float* query = (const float*)d_in[0];
  const float* key = (const float*)d_in[1];
  const float* value = (const float*)d_in[2];
  const float* Wq = (const float*)d_in[3];
  const float* bq = (const float*)d_in[4];
  const float* Wk = (const float*)d_in[5];
  const float* bk = (const float*)d_in[6];
  const float* Wv = (const float*)d_in[7];
  const float* bv = (const float*)d_in[8];
  const float* Wo = (const float*)d_in[9];
  const float* bo = (const float*)d_in[10];
  float* out = (float*)d_out;

  char* ws = (char*)d_ws;
  size_t off = 0;
  auto alloc = [&](size_t bytes) {
    void* p = ws + off;
    off += (bytes + 255) & ~(size_t)255;
    return p;
  };
  unsigned short* Wq_b = (unsigned short*)alloc((size_t)1024 * 1024 * 2);
  unsigned short* Wk_b = (unsigned short*)alloc((size_t)1024 * 1024 * 2);
  unsigned short* Wv_b = (unsigned short*)alloc((size_t)1024 * 1024 * 2);
  unsigned short* Wo_b = (unsigned short*)alloc((size_t)1024 * 1024 * 2);
  unsigned short* query_b = (unsigned short*)alloc((size_t)128 * 1024 * 2);
  unsigned short* q_hd = (unsigned short*)alloc((size_t)128 * 1024 * 2);
  unsigned short* attn_b = (unsigned short*)alloc((size_t)128 * 1024 * 2);
  float* part_O = (float*)alloc((size_t)128 * SPLIT * 16 * 64 * 4);
  float* part_ml = (float*)alloc((size_t)128 * SPLIT * 32 * 4);
  unsigned short* k_hd = (unsigned short*)alloc((size_t)128 * LKK * 64 * 2);
  unsigned short* v_t = (unsigned short*)alloc((size_t)128 * LKK * 64 * 2);
  unsigned short* stage = (unsigned short*)alloc((size_t)65536 * 1024 * 2);

  // Weights -> bf16 (4 MB each fp32; 1M elems -> 1024 blocks each)
  cvt2<<<dim3(1024, 2), 256, 0, stream>>>(Wq, Wk, Wq_b, Wk_b);
  cvt2<<<dim3(1024, 2), 256, 0, stream>>>(Wv, Wo, Wv_b, Wo_b);
  // query -> bf16 (131072 elems -> 128 blocks)
  cvt2<<<dim3(128, 1), 256, 0, stream>>>(query, nullptr, query_b, nullptr);

  // Q proj: M=128, scale=1/sqrt(64) folded, layout [b][h][16][64]
  gemm_nt<1, 4><<<dim3(1, 8), 256, 0, stream>>>(query_b, Wq_b, bq, 0.125f, q_hd);

  // key -> bf16 -> K proj (layout [b][h][8192][64])
  cvt2<<<dim3(65536, 1), 256, 0, stream>>>(key, nullptr, stage, nullptr);
  gemm_nt<1, 13><<<dim3(512, 8), 256, 0, stream>>>(stage, Wk_b, bk, 1.0f, k_hd);

  // value -> bf16 (reuse stage) -> V proj (transposed layout [b][h][64][8192])
  cvt2<<<dim3(65536, 1), 256, 0, stream>>>(value, nullptr, stage, nullptr);
  gemm_nt<2, 13><<<dim3(512, 8), 256, 0, stream>>>(stage, Wv_b, bv, 1.0f, v_t);

  // Attention (split-K) + merge -> bf16 activations
  attn_split<<<dim3(16, 8, SPLIT), 256, 0, stream>>>(q_hd, k_hd, v_t, part_O, part_ml);
  attn_merge<<<128, 256, 0, stream>>>(part_O, part_ml, attn_b);

  // Output projection -> d_out fp32 [8,16,1024]
  gemm_nt<0, 0><<<dim3(1, 8), 256, 0, stream>>>(attn_b, Wo_b, bo, 1.0f, out);
}

// Round 3
// 937.267 us; speedup vs baseline: 1.1287x; 1.1287x over previous
//
#include <hip/hip_runtime.h>
#include <stdint.h>

#define NHEADS 16
#define LKK 8192
#define SPLIT 8
#define PSTR 72  // padded LDS row stride (shorts) for P tiles: conflict-free b128 reads

typedef __attribute__((ext_vector_type(8))) short short8;
typedef __attribute__((ext_vector_type(4))) float f32x4;
typedef __attribute__((ext_vector_type(4))) unsigned short ushort4v;

__device__ __forceinline__ unsigned short f2bf(float f) {
  union { float f; unsigned u; } v; v.f = f;
  unsigned u = v.u;
  return (unsigned short)((u + 0x7fffu + ((u >> 16) & 1u)) >> 16);
}

__device__ __forceinline__ void async_ld16(const void* g, void* l) {
  __builtin_amdgcn_global_load_lds(
      (const __attribute__((address_space(1))) unsigned int*)g,
      (__attribute__((address_space(3))) unsigned int*)l, 16, 0, 0);
}

// Convert up to two fp32 tensors to bf16. gridDim.y selects tensor; each
// block handles 1024 elements (256 threads x float4).
__global__ __launch_bounds__(256) void cvt2(const float* __restrict__ a,
                                            const float* __restrict__ b,
                                            unsigned short* __restrict__ oa,
                                            unsigned short* __restrict__ ob) {
  const float* s = blockIdx.y ? b : a;
  unsigned short* d = blockIdx.y ? ob : oa;
  const size_t i = ((size_t)blockIdx.x * 256 + threadIdx.x) * 4;
  float4 v = *(const float4*)(s + i);
  ushort4v o = {f2bf(v.x), f2bf(v.y), f2bf(v.z), f2bf(v.w)};
  *(ushort4v*)(d + i) = o;
}

// ---------------------------------------------------------------------------
// Big NT GEMM: C = A(bf16,[M x 1024]) @ Bw(bf16,[1024 x 1024])^T + bias.
// 256x256 tile, BK=64, 8 waves (2M x 4N), 512 threads, 8-phase-style schedule:
// per K-tile 4 phases x {ds_read frags | stage 2 quarter-tiles of tile t+1 |
// barrier | MFMA x16 (setprio) | barrier}, counted vmcnt (2 at boundary, 4
// mid-group) - never drained to 0 in steady state.
// LDS: 2 buffers x (A[256][64] + B[256][64]) bf16 = 128 KiB, XOR-swizzled
// (byte ^= (row&7)<<4) via pre-swizzled GLOBAL source + swizzled reads
// (global_load_lds dest must stay linear).
// Race-freedom: tile t+1 staged during group g(t) into buffer of tile t-1
// (reads finished before g(t) began); reads of t+1 gated by boundary
// vmcnt(2)+barrier (loads 1-6: B.q0-3, A.q0, A.q2) and mid-group vmcnt(4)
// (loads 7-8: A.q1, A.q3, needed from phase 3).
// MODE 1: bf16 out [b][h][8192][64]. MODE 2: bf16 out [b][h][64][8192].
// ---------------------------------------------------------------------------
#define MM(MI, A0, A1)                                                        \
  {                                                                           \
    _Pragma("unroll") for (int n = 0; n < 4; ++n) {                           \
      acc[MI][n] = __builtin_amdgcn_mfma_f32_16x16x32_bf16(A0, bf[n][0],      \
                                                           acc[MI][n], 0, 0, 0); \
      acc[MI][n] = __builtin_amdgcn_mfma_f32_16x16x32_bf16(A1, bf[n][1],      \
                                                           acc[MI][n], 0, 0, 0); \
    }                                                                         \
  }

template <int MODE>
__global__ __launch_bounds__(512) void gemm_big(
    const unsigned short* __restrict__ A, const unsigned short* __restrict__ Bw,
    const float* __restrict__ bias, unsigned short* __restrict__ O) {
  __shared__ __align__(16) unsigned short lds[2][2][256 * 64];  // [buf][A/B]

  const int tid = threadIdx.x;
  const int wave = tid >> 6, lane = tid & 63;
  const int quad = lane >> 4, l16 = lane & 15, l7 = l16 & 7;
  const int wr = wave >> 2, wc = wave & 3;

  // XCD swizzle (nwg = 1024, bijective) then bn fastest for L2 reuse.
  int id = blockIdx.x;
  id = (id & 7) * 128 + (id >> 3);
  const int bm = id >> 2, bn = id & 3;
  const int row0 = bm * 256, col0 = bn * 256;

  // Staging source: thread t covers local row lr = t>>3 of a 64-row quarter,
  // 16B segment (t&7). Pre-swizzle: fetch global segment (t&7) ^ (lr&7) so
  // the linear LDS landing slot holds XOR-swizzled content.
  const int lr = tid >> 3;
  const int seg_src = (tid & 7) ^ (lr & 7);
  const unsigned short* Asrc = A + (size_t)(row0 + lr) * 1024 + seg_src * 8;
  const unsigned short* Bsrc = Bw + (size_t)(col0 + lr) * 1024 + seg_src * 8;

  f32x4 acc[8][4] = {};
  short8 bf[4][2];

#define STG(MAT, NXT, KT, Q)                                                  \
  async_ld16(((MAT) ? Bsrc : Asrc) + (size_t)(Q) * 64 * 1024 + (KT) * 64,     \
             &lds[NXT][MAT][(Q) * 4096 + wave * 512])
#define BARX() asm volatile("s_barrier" ::: "memory")
// swizzled reads: logical 16B-segment (ks*4+quad) -> physical ^ (row&7)=l7
#define RD_A(MI, KS)                                                          \
  (*(const short8*)(ldsA + (wr * 128 + (MI) * 16 + l16) * 64 +                \
                    ((((KS) * 4 + quad) ^ l7) * 8)))
#define RD_B(NN, KS)                                                          \
  (*(const short8*)(ldsB + (wc * 64 + (NN) * 16 + l16) * 64 +                 \
                    ((((KS) * 4 + quad) ^ l7) * 8)))

  // prologue: tile 0 -> buf 0; issue order B.q0-3, A.q0, A.q2, A.q1, A.q3
  STG(1, 0, 0, 0); STG(1, 0, 0, 1); STG(1, 0, 0, 2); STG(1, 0, 0, 3);
  STG(0, 0, 0, 0); STG(0, 0, 0, 2); STG(0, 0, 0, 1); STG(0, 0, 0, 3);
  asm volatile("s_waitcnt vmcnt(2)" ::: "memory");
  BARX();

#pragma unroll 2
  for (int kt = 0; kt < 16; ++kt) {
    const int cur = kt & 1, nxt = cur ^ 1;
    const bool pf = kt < 15;
    const unsigned short* ldsA = &lds[cur][0][0];
    const unsigned short* ldsB = &lds[cur][1][0];

    // phase 1: mi {0,1}; load all B frags (held for the group); stage B.q0,q1
    {
#pragma unroll
      for (int n = 0; n < 4; ++n) { bf[n][0] = RD_B(n, 0); bf[n][1] = RD_B(n, 1); }
      short8 a0 = RD_A(0, 0), a1 = RD_A(0, 1), a2 = RD_A(1, 0), a3 = RD_A(1, 1);
      if (pf) { STG(1, nxt, kt + 1, 0); STG(1, nxt, kt + 1, 1); }
      BARX();
      __builtin_amdgcn_s_setprio(1);
      MM(0, a0, a1); MM(1, a2, a3);
      __builtin_amdgcn_s_setprio(0);
      BARX();
    }
    // phase 2: mi {2,3}; stage B.q2,q3; vmcnt forces prev-group A.q1,A.q3
    {
      short8 a0 = RD_A(2, 0), a1 = RD_A(2, 1), a2 = RD_A(3, 0), a3 = RD_A(3, 1);
      if (pf) { STG(1, nxt, kt + 1, 2); STG(1, nxt, kt + 1, 3); }
      BARX();
      __builtin_amdgcn_s_setprio(1);
      MM(2, a0, a1); MM(3, a2, a3);
      __builtin_amdgcn_s_setprio(0);
      if (pf) asm volatile("s_waitcnt vmcnt(4)" ::: "memory");
      else    asm volatile("s_waitcnt vmcnt(0)" ::: "memory");
      BARX();
    }
    // phase 3: mi {4,5}; stage A.q0,A.q2 (needed first next group)
    {
      short8 a0 = RD_A(4, 0), a1 = RD_A(4, 1), a2 = RD_A(5, 0), a3 = RD_A(5, 1);
      if (pf) { STG(0, nxt, kt + 1, 0); STG(0, nxt, kt + 1, 2); }
      BARX();
      __builtin_amdgcn_s_setprio(1);
      MM(4, a0, a1); MM(5, a2, a3);
      __builtin_amdgcn_s_setprio(0);
      BARX();
    }
    // phase 4: mi {6,7}; stage A.q1,A.q3; boundary vmcnt(2) (leaves them in flight)
    {
      short8 a0 = RD_A(6, 0), a1 = RD_A(6, 1), a2 = RD_A(7, 0), a3 = RD_A(7, 1);
      if (pf) { STG(0, nxt, kt + 1, 1); STG(0, nxt, kt + 1, 3); }
      BARX();
      __builtin_amdgcn_s_setprio(1);
      MM(6, a0, a1); MM(7, a2, a3);
      __builtin_amdgcn_s_setprio(0);
      if (pf) asm volatile("s_waitcnt vmcnt(2)" ::: "memory");
      BARX();
    }
  }
#undef RD_A
#undef RD_B
#undef STG

  float bvals[4];
#pragma unroll
  for (int n = 0; n < 4; ++n) bvals[n] = bias[col0 + wc * 64 + n * 16 + l16];

#pragma unroll
  for (int mi = 0; mi < 8; ++mi) {
    const int gm0 = row0 + wr * 128 + mi * 16 + quad * 4;
#pragma unroll
    for (int n = 0; n < 4; ++n) {
      const int gn = col0 + wc * 64 + n * 16 + l16;
      const int h = gn >> 6, d = gn & 63;
      float vals[4];
#pragma unroll
      for (int r = 0; r < 4; ++r) vals[r] = acc[mi][n][r] + bvals[n];
      if constexpr (MODE == 1) {
#pragma unroll
        for (int r = 0; r < 4; ++r) {
          const int m = gm0 + r;
          const int bb = m >> 13, x = m & 8191;
          O[((((size_t)(bb * 16 + h)) << 13) + x) * 64 + d] = f2bf(vals[r]);
        }
      } else {
        const int bb = gm0 >> 13, x = gm0 & 8191;
        ushort4v pk = {f2bf(vals[0]), f2bf(vals[1]), f2bf(vals[2]), f2bf(vals[3])};
        *(ushort4v*)(O + ((((size_t)(bb * 16 + h)) * 64 + d) << 13) + x) = pk;
      }
    }
  }
}

// ---------------------------------------------------------------------------
// Small NT GEMM (M=128): unchanged verified 128x128 kernel.
// ---------------------------------------------------------------------------
template <int MODE, int LOG2ROWS>
__global__ __launch_bounds__(256) void gemm_nt(
    const unsigned short* __restrict__ A, const unsigned short* __restrict__ Bw,
    const float* __restrict__ bias, float scale, void* __restrict__ outp) {
  __shared__ unsigned short As[128 * 32];
  __shared__ unsigned short Bs[128 * 32];

  const int tid = threadIdx.x;
  const int wave = tid >> 6, lane = tid & 63;
  const int quad = lane >> 4, l16 = lane & 15;
  const int wr = wave >> 1, wc = wave & 1;

  const int gx = gridDim.x;
  const int nwg = gx * 8;
  int id = blockIdx.y * gx + blockIdx.x;
  const int cpx = nwg >> 3;
  id = (id & 7) * cpx + (id >> 3);
  const int bm = id >> 3, bn = id & 7;

  f32x4 acc[4][4] = {};

  const int srow = lane >> 2;
  const int sseg = lane & 3;
  const unsigned short* Ag =
      A + (size_t)(bm * 128 + wave * 32 + srow) * 1024 + sseg * 8;
  const unsigned short* Bg =
      Bw + (size_t)(bn * 128 + wave * 32 + srow) * 1024 + sseg * 8;
  unsigned short* AsW = As + wave * 32 * 32;
  unsigned short* BsW = Bs + wave * 32 * 32;

  for (int kk = 0; kk < 32; ++kk) {
    const int k0 = kk * 32;
    __syncthreads();
    async_ld16(Ag + k0, AsW);
    async_ld16(Ag + 16 * 1024 + k0, AsW + 16 * 32);
    async_ld16(Bg + k0, BsW);
    async_ld16(Bg + 16 * 1024 + k0, BsW + 16 * 32);
    __syncthreads();

    short8 af[4], bfr[4];
#pragma unroll
    for (int i = 0; i < 4; ++i)
      af[i] = *(const short8*)(As + (wr * 64 + i * 16 + l16) * 32 + quad * 8);
#pragma unroll
    for (int j = 0; j < 4; ++j)
      bfr[j] = *(const short8*)(Bs + (wc * 64 + j * 16 + l16) * 32 + quad * 8);
#pragma unroll
    for (int i = 0; i < 4; ++i)
#pragma unroll
      for (int j = 0; j < 4; ++j)
        acc[i][j] =
            __builtin_amdgcn_mfma_f32_16x16x32_bf16(af[i], bfr[j], acc[i][j], 0, 0, 0);
  }

  float bvals[4];
#pragma unroll
  for (int j = 0; j < 4; ++j) bvals[j] = bias[bn * 128 + wc * 64 + j * 16 + l16];

#pragma unroll
  for (int i = 0; i < 4; ++i) {
    const int gm0 = bm * 128 + wr * 64 + i * 16 + quad * 4;
#pragma unroll
    for (int j = 0; j < 4; ++j) {
      const int gn = bn * 128 + wc * 64 + j * 16 + l16;
      float vals[4];
#pragma unroll
      for (int r = 0; r < 4; ++r) vals[r] = (acc[i][j][r] + bvals[j]) * scale;
      if constexpr (MODE == 0) {
        float* Of = (float*)outp;
#pragma unroll
        for (int r = 0; r < 4; ++r) Of[(size_t)(gm0 + r) * 1024 + gn] = vals[r];
      } else if constexpr (MODE == 1) {
        unsigned short* Ou = (unsigned short*)outp;
        const int h = gn >> 6, d = gn & 63;
#pragma unroll
        for (int r = 0; r < 4; ++r) {
          const int m = gm0 + r;
          const int bb = m >> LOG2ROWS;
          const int x = m & ((1 << LOG2ROWS) - 1);
          Ou[((((size_t)(bb * 16 + h)) << LOG2ROWS) + x) * 64 + d] = f2bf(vals[r]);
        }
      } else {
        unsigned short* Ou = (unsigned short*)outp;
        const int h = gn >> 6, d = gn & 63;
        const int bb = gm0 >> LOG2ROWS;
        const int x = gm0 & ((1 << LOG2ROWS) - 1);
        ushort4v pk = {f2bf(vals[0]), f2bf(vals[1]), f2bf(vals[2]), f2bf(vals[3])};
        *(ushort4v*)(Ou + ((((size_t)(bb * 16 + h)) * 64 + d) << LOG2ROWS) + x) = pk;
      }
    }
  }
}

// Split-K flash attention: grid (h=16, b=8, s=SPLIT), 256 threads. Unchanged.
__global__ __launch_bounds__(256) void attn_split(
    const unsigned short* __restrict__ q_hd,  // [B][H][16][64] bf16 (scale folded)
    const unsigned short* __restrict__ k_hd,  // [B][H][8192][64] bf16
    const unsigned short* __restrict__ v_t,   // [B][H][64][8192] bf16
    float* __restrict__ part_O,               // [B*H][SPLIT][16][64]
    float* __restrict__ part_ml)              // [B*H][SPLIT][2][16]
{
  __shared__ unsigned short p_lds[4][16 * PSTR];
  __shared__ float o_lds[4][16][64];
  __shared__ float ml_lds[4][2][16];

  const int h = blockIdx.x, b = blockIdx.y, sp = blockIdx.z;
  const int tid = threadIdx.x, wave = tid >> 6, lane = tid & 63;
  const int quad = lane >> 4, l16 = lane & 15;
  const size_t bh = (size_t)(b * NHEADS + h);
  const float LOG2E = 1.44269504088896f;

  const unsigned short* qb = q_hd + bh * (16 * 64) + l16 * 64 + quad * 8;
  short8 aq0 = *(const short8*)(qb);
  short8 aq1 = *(const short8*)(qb + 32);

  const unsigned short* kb_base = k_hd + bh * ((size_t)LKK * 64);
  const unsigned short* vb_base = v_t + bh * ((size_t)64 * LKK);

  float ms[4], ls[4];
  f32x4 o[4] = {};
#pragma unroll
  for (int r = 0; r < 4; ++r) { ms[r] = -3.0e38f; ls[r] = 0.f; }

  unsigned short* pw = &p_lds[wave][0];
  const int jbase = sp * (LKK / SPLIT) + wave * (LKK / SPLIT / 4);

  for (int c = 0; c < (LKK / SPLIT / 4) / 64; ++c) {
    const int j0 = jbase + c * 64;
    short8 kf[4][2];
#pragma unroll
    for (int jt = 0; jt < 4; ++jt)
#pragma unroll
      for (int dh = 0; dh < 2; ++dh)
        kf[jt][dh] = *(const short8*)(kb_base + (size_t)(j0 + jt * 16 + l16) * 64 +
                                      dh * 32 + quad * 8);
    f32x4 s[4];
#pragma unroll
    for (int jt = 0; jt < 4; ++jt) {
      f32x4 z = {};
      z = __builtin_amdgcn_mfma_f32_16x16x32_bf16(aq0, kf[jt][0], z, 0, 0, 0);
      z = __builtin_amdgcn_mfma_f32_16x16x32_bf16(aq1, kf[jt][1], z, 0, 0, 0);
      s[jt] = z;
    }
    float p[4][4], alpha[4];
#pragma unroll
    for (int r = 0; r < 4; ++r) {
      float v = fmaxf(fmaxf(s[0][r], s[1][r]), fmaxf(s[2][r], s[3][r]));
      v = fmaxf(v, __shfl_xor(v, 1));
      v = fmaxf(v, __shfl_xor(v, 2));
      v = fmaxf(v, __shfl_xor(v, 4));
      v = fmaxf(v, __shfl_xor(v, 8));
      const float mn = fmaxf(ms[r], v);
      alpha[r] = __builtin_amdgcn_exp2f((ms[r] - mn) * LOG2E);
      float rs = 0.f;
#pragma unroll
      for (int jt = 0; jt < 4; ++jt) {
        p[jt][r] = __builtin_amdgcn_exp2f((s[jt][r] - mn) * LOG2E);
        rs += p[jt][r];
      }
      ls[r] = ls[r] * alpha[r] + rs;
      ms[r] = mn;
    }
#pragma unroll
    for (int dt = 0; dt < 4; ++dt) {
      f32x4 t = o[dt];
      t[0] *= alpha[0]; t[1] *= alpha[1]; t[2] *= alpha[2]; t[3] *= alpha[3];
      o[dt] = t;
    }
#pragma unroll
    for (int r = 0; r < 4; ++r)
#pragma unroll
      for (int jt = 0; jt < 4; ++jt)
        pw[(quad * 4 + r) * PSTR + jt * 16 + l16] = f2bf(p[jt][r]);
    short8 pa[2];
#pragma unroll
    for (int kt = 0; kt < 2; ++kt)
      pa[kt] = *(const short8*)(pw + l16 * PSTR + kt * 32 + quad * 8);
#pragma unroll
    for (int dt = 0; dt < 4; ++dt)
#pragma unroll
      for (int kt = 0; kt < 2; ++kt) {
        short8 vb = *(const short8*)(vb_base + (size_t)(dt * 16 + l16) * LKK + j0 +
                                     kt * 32 + quad * 8);
        o[dt] = __builtin_amdgcn_mfma_f32_16x16x32_bf16(pa[kt], vb, o[dt], 0, 0, 0);
      }
  }

#pragma unroll
  for (int r = 0; r < 4; ++r) {
    ls[r] += __shfl_xor(ls[r], 1);
    ls[r] += __shfl_xor(ls[r], 2);
    ls[r] += __shfl_xor(ls[r], 4);
    ls[r] += __shfl_xor(ls[r], 8);
  }

#pragma unroll
  for (int dt = 0; dt < 4; ++dt)
#pragma unroll
    for (int r = 0; r < 4; ++r) o_lds[wave][quad * 4 + r][dt * 16 + l16] = o[dt][r];
  if (l16 == 0) {
#pragma unroll
    for (int r = 0; r < 4; ++r) {
      ml_lds[wave][0][quad * 4 + r] = ms[r];
      ml_lds[wave][1][quad * 4 + r] = ls[r];
    }
  }
  __syncthreads();

  const int q = tid >> 4;
  const int d0 = (tid & 15) * 4;
  float mstar = ml_lds[0][0][q];
#pragma unroll
  for (int w = 1; w < 4; ++w) mstar = fmaxf(mstar, ml_lds[w][0][q]);
  float lstar = 0.f, ov[4] = {0.f, 0.f, 0.f, 0.f};
#pragma unroll
  for (int w = 0; w < 4; ++w) {
    const float sc = __builtin_amdgcn_exp2f((ml_lds[w][0][q] - mstar) * LOG2E);
    lstar += ml_lds[w][1][q] * sc;
#pragma unroll
    for (int e = 0; e < 4; ++e) ov[e] += o_lds[w][q][d0 + e] * sc;
  }
  const size_t base = (bh * SPLIT + sp);
#pragma unroll
  for (int e = 0; e < 4; ++e) part_O[base * 1024 + q * 64 + d0 + e] = ov[e];
  if (d0 == 0) {
    part_ml[base * 32 + q] = mstar;
    part_ml[base * 32 + 16 + q] = lstar;
  }
}

// Merge SPLIT partials -> bf16 attn activations [B*16][1024].
__global__ __launch_bounds__(256) void attn_merge(const float* __restrict__ part_O,
                                                  const float* __restrict__ part_ml,
                                                  unsigned short* __restrict__ attn_b) {
  const int bh = blockIdx.x;
  const int b = bh >> 4, h = bh & 15;
  const int q = threadIdx.x >> 4;
  const int d0 = (threadIdx.x & 15) * 4;
  const float LOG2E = 1.44269504088896f;

  float mstar = -3.0e38f;
#pragma unroll
  for (int s = 0; s < SPLIT; ++s)
    mstar = fmaxf(mstar, part_ml[((size_t)bh * SPLIT + s) * 32 + q]);
  float lsum = 0.f, ov[4] = {0.f, 0.f, 0.f, 0.f};
#pragma unroll
  for (int s = 0; s < SPLIT; ++s) {
    const size_t base = (size_t)bh * SPLIT + s;
    const float sc = __builtin_amdgcn_exp2f((part_ml[base * 32 + q] - mstar) * LOG2E);
    lsum += part_ml[base * 32 + 16 + q] * sc;
#pragma unroll
    for (int e = 0; e < 4; ++e) ov[e] += part_O[base * 1024 + q * 64 + d0 + e] * sc;
  }
  const float inv = 1.0f / lsum;
  ushort4v pk = {f2bf(ov[0] * inv), f2bf(ov[1] * inv), f2bf(ov[2] * inv),
                 f2bf(ov[3] * inv)};
  *(ushort4v*)(attn_b + (size_t)(b * 16 + q) * 1024 + h * 64 + d0) = pk;
}

extern "C" void kernel_launch(void* const* d_in, const int* in_sizes, int n_in,
                              void* d_out, int out_size, void* d_ws, size_t ws_size,
                              hipStream_t stream) {
  const float* query = (const float*)d_in[0];
  const float* key = (const float*)d_in[1];
  const float* value = (const float*)d_in[2];
  const float* Wq = (const float*)d_in[3];
  const float* bq = (const float*)d_in[4];
  const float* Wk = (const float*)d_in[5];
  const float* bk = (const float*)d_in[6];
  const float* Wv = (const float*)d_in[7];
  const float* bv = (const float*)d_in[8];
  const float* Wo = (const float*)d_in[9];
  const float* bo = (const float*)d_in[10];
  float* out = (float*)d_out;

  char* ws = (char*)d_ws;
  size_t off = 0;
  auto alloc = [&](size_t bytes) {
    void* p = ws + off;
    off += (bytes + 255) & ~(size_t)255;
    return p;
  };
  unsigned short* Wq_b = (unsigned short*)alloc((size_t)1024 * 1024 * 2);
  unsigned short* Wk_b = (unsigned short*)alloc((size_t)1024 * 1024 * 2);
  unsigned short* Wv_b = (unsigned short*)alloc((size_t)1024 * 1024 * 2);
  unsigned short* Wo_b = (unsigned short*)alloc((size_t)1024 * 1024 * 2);
  unsigned short* query_b = (unsigned short*)alloc((size_t)128 * 1024 * 2);
  unsigned short* q_hd = (unsigned short*)alloc((size_t)128 * 1024 * 2);
  unsigned short* attn_b = (unsigned short*)alloc((size_t)128 * 1024 * 2);
  float* part_O = (float*)alloc((size_t)128 * SPLIT * 16 * 64 * 4);
  float* part_ml = (float*)alloc((size_t)128 * SPLIT * 32 * 4);
  unsigned short* k_hd = (unsigned short*)alloc((size_t)128 * LKK * 64 * 2);
  unsigned short* v_t = (unsigned short*)alloc((size_t)128 * LKK * 64 * 2);
  unsigned short* stage = (unsigned short*)alloc((size_t)65536 * 1024 * 2);

  // Weights -> bf16
  cvt2<<<dim3(1024, 2), 256, 0, stream>>>(Wq, Wk, Wq_b, Wk_b);
  cvt2<<<dim3(1024, 2), 256, 0, stream>>>(Wv, Wo, Wv_b, Wo_b);
  cvt2<<<dim3(128, 1), 256, 0, stream>>>(query, nullptr, query_b, nullptr);

  // Q proj: M=128, scale=1/sqrt(64) folded, layout [b][h][16][64]
  gemm_nt<1, 4><<<dim3(1, 8), 256, 0, stream>>>(query_b, Wq_b, bq, 0.125f, q_hd);

  // key -> bf16 -> K proj (8-phase 256^2 kernel, layout [b][h][8192][64])
  cvt2<<<dim3(65536, 1), 256, 0, stream>>>(key, nullptr, stage, nullptr);
  gemm_big<1><<<dim3(1024), 512, 0, stream>>>(stage, Wk_b, bk, k_hd);

  // value -> bf16 -> V proj (transposed layout [b][h][64][8192])
  cvt2<<<dim3(65536, 1), 256, 0, stream>>>(value, nullptr, stage, nullptr);
  gemm_big<2><<<dim3(1024), 512, 0, stream>>>(stage, Wv_b, bv, v_t);

  // Attention (split-K) + merge -> bf16 activations
  attn_split<<<dim3(16, 8, SPLIT), 256, 0, stream>>>(q_hd, k_hd, v_t, part_O, part_ml);
  attn_merge<<<128, 256, 0, stream>>>(part_O, part_ml, attn_b);

  // Output projection -> d_out fp32 [8,16,1024]
  gemm_nt<0, 0><<<dim3(1, 8), 256, 0, stream>>>(attn_b, Wo_b, bo, 1.0f, out);
}